// Round 1
// baseline (245.456 us; speedup 1.0000x reference)
//
#include <hip/hip_runtime.h>
#include <math.h>

#define B_ 4096
#define T_ 128
#define S_ 16
#define C_ 128
#define L_ 33            // 2*S+1
#define NEGV (-1e30f)

__device__ __forceinline__ float lae(float a, float b) {
    // logaddexp in fp32, mirrors jnp.logaddexp for finite inputs
    float m = fmaxf(a, b);
    float d = fabsf(a - b);
    return m + log1pf(expf(-d));
}

__global__ __launch_bounds__(64) void ctc_alpha_kernel(
        const float* __restrict__ pred,   // (B, T, C) log-probs
        const float* __restrict__ lab,    // (B, S, C)
        float* __restrict__ out_b) {      // (B,) nll/S
    const int b = blockIdx.x;
    const int lane = threadIdx.x;

    // ---- Phase A: targets[s] = argmax_c lab[b,s,c], first-max-index tie-break ----
    __shared__ int tgt[S_];
    const float* lrow = lab + (size_t)b * S_ * C_;
    for (int s = 0; s < S_; ++s) {
        float v0 = lrow[s * C_ + lane];
        float v1 = lrow[s * C_ + lane + 64];
        float v; int idx;
        if (v1 > v0) { v = v1; idx = lane + 64; } else { v = v0; idx = lane; }
        #pragma unroll
        for (int off = 32; off >= 1; off >>= 1) {
            float ov = __shfl_xor(v, off, 64);
            int   oi = __shfl_xor(idx, off, 64);
            if (ov > v || (ov == v && oi < idx)) { v = ov; idx = oi; }
        }
        if (lane == 0) tgt[s] = idx;
    }
    __syncthreads();

    // ---- Phase B: extended label + skip_ok for this lane's state ----
    const int l = lane;
    int cls = 0;
    if (l < L_ && (l & 1)) cls = tgt[(l - 1) >> 1];
    bool skip = false;
    if (l >= 3 && l < L_ && (l & 1)) {
        int c2 = tgt[(l - 3) >> 1];      // ext[l-2]
        skip = (cls != c2);
    }

    // ---- Phase C: alpha recursion over T ----
    const float* p = pred + (size_t)b * T_ * C_ + cls;
    float lp0 = p[0];
    float alpha = (l == 0 || l == 1) ? lp0 : NEGV;

    float lp_next = p[C_];               // prefetch t=1
    for (int t = 1; t < T_; ++t) {
        float lp = lp_next;
        if (t + 1 < T_) lp_next = p[(size_t)(t + 1) * C_];
        float a2 = __shfl_up(alpha, 1, 64);
        float a3 = __shfl_up(alpha, 2, 64);
        if (l < 1)  a2 = NEGV;           // no lane below 0
        if (!skip)  a3 = NEGV;           // skip transition gated
        alpha = lae(lae(alpha, a2), a3) + lp;
    }

    float aL1 = __shfl(alpha, L_ - 1, 64);
    float aL2 = __shfl(alpha, L_ - 2, 64);
    if (lane == 0) {
        float nll = -lae(aL1, aL2);
        if (!isfinite(nll)) nll = 0.0f;  // zero_infinity
        out_b[b] = nll / (float)S_;
    }
}

__global__ __launch_bounds__(256) void reduce_mean_kernel(
        const float* __restrict__ in, float* __restrict__ out) {
    __shared__ float sm[256];
    const int tid = threadIdx.x;
    float s = 0.f;
    for (int i = tid; i < B_; i += 256) s += in[i];   // fixed order: deterministic
    sm[tid] = s;
    __syncthreads();
    for (int w = 128; w >= 1; w >>= 1) {
        if (tid < w) sm[tid] += sm[tid + w];
        __syncthreads();
    }
    if (tid == 0) out[0] = sm[0] / (float)B_;
}

extern "C" void kernel_launch(void* const* d_in, const int* in_sizes, int n_in,
                              void* d_out, int out_size, void* d_ws, size_t ws_size,
                              hipStream_t stream) {
    const float* pred = (const float*)d_in[0];  // (B,T,C) fp32
    const float* lab  = (const float*)d_in[1];  // (B,S,C) fp32
    float* ws = (float*)d_ws;                   // B floats of scratch
    ctc_alpha_kernel<<<B_, 64, 0, stream>>>(pred, lab, ws);
    reduce_mean_kernel<<<1, 256, 0, stream>>>(ws, (float*)d_out);
}

// Round 2
// 89.291 us; speedup vs baseline: 2.7489x; 2.7489x over previous
//
#include <hip/hip_runtime.h>
#include <math.h>

#define B_ 4096
#define T_ 128
#define S_ 16
#define C_ 128
#define L_ 33            // 2*S+1
#define NEGV (-1e30f)
#define LOG2E 1.4426950408889634f
#define LN2 0.6931471805599453f
#define NEGB (NEGV * LOG2E)   // NEG in log2 domain, still finite fp32

__device__ __forceinline__ float hexp2(float x) { return __builtin_amdgcn_exp2f(x); }
__device__ __forceinline__ float hlog2(float x) { return __builtin_amdgcn_logf(x); }

// 4 waves per block, one batch element per wave.
__global__ __launch_bounds__(256) void ctc_alpha_kernel(
        const float* __restrict__ pred,   // (B, T, C) log-probs
        const float* __restrict__ lab,    // (B, S, C)
        float* __restrict__ out_b) {      // (B,) nll/S
    const int wid  = threadIdx.x >> 6;
    const int lane = threadIdx.x & 63;
    const int b = blockIdx.x * 4 + wid;

    // ---- Phase A: targets[s] = argmax_c lab[b,s,c], first-index tie-break ----
    __shared__ int tgt[4][S_];
    const float* lrow = lab + (size_t)b * S_ * C_;
    #pragma unroll
    for (int s = 0; s < S_; ++s) {
        float v0 = lrow[s * C_ + lane];
        float v1 = lrow[s * C_ + lane + 64];
        float v; int idx;
        if (v1 > v0) { v = v1; idx = lane + 64; } else { v = v0; idx = lane; }
        #pragma unroll
        for (int off = 32; off >= 1; off >>= 1) {
            float ov = __shfl_xor(v, off, 64);
            int   oi = __shfl_xor(idx, off, 64);
            if (ov > v || (ov == v && oi < idx)) { v = ov; idx = oi; }
        }
        if (lane == 0) tgt[wid][s] = idx;
    }
    __syncthreads();

    // ---- Phase B: extended label + skip_ok for this lane's state ----
    const int l = lane;
    int cls = 0;
    bool skipv = false;
    if (l < L_ && (l & 1)) {
        cls = tgt[wid][(l - 1) >> 1];
        if (l >= 3) skipv = (cls != tgt[wid][(l - 3) >> 1]);
    }
    const bool has2 = (l >= 1);

    // ---- Phase C: alpha recursion over T, in log2 domain ----
    const float* p = pred + (size_t)b * T_ * C_ + cls;
    float beta = (l <= 1) ? p[0] * LOG2E : NEGB;

    // 3-deep prefetch ring for the per-step gather
    float lpA = p[C_];
    float lpB = p[2 * C_];
    float lpC = p[3 * C_];
    for (int t = 1; t < T_; ++t) {
        float lp = lpA; lpA = lpB; lpB = lpC;
        if (t + 3 < T_) lpC = p[(size_t)(t + 3) * C_];
        float a2 = __shfl_up(beta, 1, 64);
        float a3 = __shfl_up(beta, 2, 64);
        a2 = has2  ? a2 : NEGB;
        a3 = skipv ? a3 : NEGB;
        float m = fmaxf(fmaxf(beta, a2), a3);   // fuses to v_max3_f32
        float s = hexp2(beta - m) + hexp2(a2 - m) + hexp2(a3 - m);
        beta = fmaf(lp, LOG2E, m + hlog2(s));
    }

    float b31 = __shfl(beta, L_ - 2, 64);
    float b32 = __shfl(beta, L_ - 1, 64);
    if (lane == 0) {
        float m = fmaxf(b31, b32);
        float lse2 = m + hlog2(hexp2(b31 - m) + hexp2(b32 - m));
        float nll = -lse2 * LN2;
        if (!isfinite(nll)) nll = 0.0f;  // zero_infinity
        out_b[b] = nll * (1.0f / (float)S_);
    }
}

__global__ __launch_bounds__(256) void reduce_mean_kernel(
        const float* __restrict__ in, float* __restrict__ out) {
    __shared__ float sm[256];
    const int tid = threadIdx.x;
    float s = 0.f;
    for (int i = tid; i < B_; i += 256) s += in[i];   // fixed order: deterministic
    sm[tid] = s;
    __syncthreads();
    for (int w = 128; w >= 1; w >>= 1) {
        if (tid < w) sm[tid] += sm[tid + w];
        __syncthreads();
    }
    if (tid == 0) out[0] = sm[0] / (float)B_;
}

extern "C" void kernel_launch(void* const* d_in, const int* in_sizes, int n_in,
                              void* d_out, int out_size, void* d_ws, size_t ws_size,
                              hipStream_t stream) {
    const float* pred = (const float*)d_in[0];  // (B,T,C) fp32
    const float* lab  = (const float*)d_in[1];  // (B,S,C) fp32
    float* ws = (float*)d_ws;                   // B floats of scratch
    ctc_alpha_kernel<<<B_ / 4, 256, 0, stream>>>(pred, lab, ws);
    reduce_mean_kernel<<<1, 256, 0, stream>>>(ws, (float*)d_out);
}

// Round 3
// 67.786 us; speedup vs baseline: 3.6210x; 1.3172x over previous
//
#include <hip/hip_runtime.h>
#include <math.h>
#include <stdint.h>

#define B_ 4096
#define T_ 128
#define S_ 16
#define C_ 128
#define L_ 33            // 2*S+1
#define NSLOT 17         // blank + 16 targets
#define NELEM (T_ * NSLOT)   // 2176 = 34 * 64
#define NEGV (-1e30f)
#define LOG2E 1.4426950408889634f
#define LN2 0.6931471805599453f
#define NEGB (NEGV * LOG2E)

__device__ __forceinline__ float hexp2(float x) { return __builtin_amdgcn_exp2f(x); }
__device__ __forceinline__ float hlog2(float x) { return __builtin_amdgcn_logf(x); }

typedef const __attribute__((address_space(1))) unsigned int* gas_t;
typedef __attribute__((address_space(3))) unsigned int* las_t;

// 4 waves per block, one batch element per wave.
__global__ __launch_bounds__(256) void ctc_alpha_kernel(
        const float* __restrict__ pred,   // (B, T, C) log-probs
        const float* __restrict__ lab,    // (B, S, C)
        float* __restrict__ out_b) {      // (B,) nll/S
    const int wid  = threadIdx.x >> 6;
    const int lane = threadIdx.x & 63;
    const int b = blockIdx.x * 4 + wid;

    __shared__ int   cls_tab[4][NSLOT];
    __shared__ float lps[4][NELEM];      // 4 x 8704 B, flat [t*17 + slot]

    // ---- Phase A: targets[s] = argmax_c lab[b,s,c], first-index tie-break ----
    // Load all 32 values first (MLP), then reduce.
    const float* lrow = lab + (size_t)b * S_ * C_;
    float v0[S_], v1[S_];
    #pragma unroll
    for (int s = 0; s < S_; ++s) {
        v0[s] = lrow[s * C_ + lane];
        v1[s] = lrow[s * C_ + lane + 64];
    }
    if (lane == 0) cls_tab[wid][0] = 0;   // blank class
    #pragma unroll
    for (int s = 0; s < S_; ++s) {
        float v; int idx;
        if (v1[s] > v0[s]) { v = v1[s]; idx = lane + 64; } else { v = v0[s]; idx = lane; }
        #pragma unroll
        for (int off = 32; off >= 1; off >>= 1) {
            float ov = __shfl_xor(v, off, 64);
            int   oi = __shfl_xor(idx, off, 64);
            if (ov > v || (ov == v && oi < idx)) { v = ov; idx = oi; }
        }
        if (lane == 0) cls_tab[wid][1 + s] = idx;
    }
    __syncthreads();

    // ---- Phase B: stage lp[t][slot] into LDS, 34 x 4B global_load_lds ----
    // Element e = i*64 + lane -> t = e/17, slot = e%17; LDS dest is linear in
    // lane (base + lane*4), matching flat [t*17+slot] layout exactly.
    const float* pb = pred + (size_t)b * T_ * C_;
    float* mylds = lps[wid];
    #pragma unroll
    for (int i = 0; i < NELEM / 64; ++i) {
        unsigned e = i * 64 + lane;
        unsigned t = e / NSLOT;
        unsigned s = e - t * NSLOT;
        int c = cls_tab[wid][s];
        const float* src = pb + (size_t)t * C_ + c;
        __builtin_amdgcn_global_load_lds((gas_t)src, (las_t)(mylds + i * 64), 4, 0, 0);
    }
    asm volatile("s_waitcnt vmcnt(0)" ::: "memory");

    // ---- Phase C: alpha recursion over T in log2 domain, lp from LDS ----
    const int l = lane;
    int cidx = 0;
    bool skipv = false;
    if (l < L_ && (l & 1)) {
        cidx = 1 + ((l - 1) >> 1);                       // slot of ext[l]
        if (l >= 3) skipv = (cls_tab[wid][cidx] != cls_tab[wid][cidx - 1]);
    }
    const bool has2 = (l >= 1);

    float beta = (l <= 1) ? mylds[cidx] * LOG2E : NEGB;  // t = 0

    float lpA = mylds[1 * NSLOT + cidx];
    float lpB = mylds[2 * NSLOT + cidx];
    float lpC = mylds[3 * NSLOT + cidx];
    #pragma unroll 4
    for (int t = 1; t < T_; ++t) {
        float lp = lpA; lpA = lpB; lpB = lpC;
        if (t + 3 < T_) lpC = mylds[(t + 3) * NSLOT + cidx];
        float a2 = __shfl_up(beta, 1, 64);
        float a3 = __shfl_up(beta, 2, 64);
        a2 = has2  ? a2 : NEGB;
        a3 = skipv ? a3 : NEGB;
        float m = fmaxf(fmaxf(beta, a2), a3);            // v_max3_f32
        float s = hexp2(beta - m) + hexp2(a2 - m) + hexp2(a3 - m);
        beta = fmaf(lp, LOG2E, m + hlog2(s));
    }

    float b31 = __shfl(beta, L_ - 2, 64);
    float b32 = __shfl(beta, L_ - 1, 64);
    if (lane == 0) {
        float m = fmaxf(b31, b32);
        float lse2 = m + hlog2(hexp2(b31 - m) + hexp2(b32 - m));
        float nll = -lse2 * LN2;
        if (!isfinite(nll)) nll = 0.0f;  // zero_infinity
        out_b[b] = nll * (1.0f / (float)S_);
    }
}

__global__ __launch_bounds__(256) void reduce_mean_kernel(
        const float* __restrict__ in, float* __restrict__ out) {
    __shared__ float sm[256];
    const int tid = threadIdx.x;
    // 16 independent loads first (MLP), then deterministic fixed-order sum.
    float v[16];
    #pragma unroll
    for (int i = 0; i < 16; ++i) v[i] = in[tid + i * 256];
    float s = 0.f;
    #pragma unroll
    for (int i = 0; i < 16; ++i) s += v[i];
    sm[tid] = s;
    __syncthreads();
    for (int w = 128; w >= 1; w >>= 1) {
        if (tid < w) sm[tid] += sm[tid + w];
        __syncthreads();
    }
    if (tid == 0) out[0] = sm[0] / (float)B_;
}

extern "C" void kernel_launch(void* const* d_in, const int* in_sizes, int n_in,
                              void* d_out, int out_size, void* d_ws, size_t ws_size,
                              hipStream_t stream) {
    const float* pred = (const float*)d_in[0];  // (B,T,C) fp32
    const float* lab  = (const float*)d_in[1];  // (B,S,C) fp32
    float* ws = (float*)d_ws;                   // B floats of scratch
    ctc_alpha_kernel<<<B_ / 4, 256, 0, stream>>>(pred, lab, ws);
    reduce_mean_kernel<<<1, 256, 0, stream>>>(ws, (float*)d_out);
}

// Round 4
// 63.102 us; speedup vs baseline: 3.8898x; 1.0742x over previous
//
#include <hip/hip_runtime.h>
#include <math.h>
#include <stdint.h>

#define B_ 4096
#define T_ 128
#define S_ 16
#define C_ 128
#define L_ 33            // 2*S+1
#define NSLOT 17         // blank + 16 targets
#define NELEM (T_ * NSLOT)   // 2176 = 34 * 64
#define NEGV (-1e30f)
#define LOG2E 1.4426950408889634f
#define LN2 0.6931471805599453f
#define NEGB (NEGV * LOG2E)

__device__ __forceinline__ float hexp2(float x) { return __builtin_amdgcn_exp2f(x); }
__device__ __forceinline__ float hlog2(float x) { return __builtin_amdgcn_logf(x); }

// monotonic float->uint map: a > b (float) <=> fkey(a) > fkey(b) (uint)
__device__ __forceinline__ unsigned fkey(float v) {
    unsigned u = __float_as_uint(v);
    return (u & 0x80000000u) ? ~u : (u | 0x80000000u);
}

typedef const __attribute__((address_space(1))) unsigned int* gas_t;
typedef __attribute__((address_space(3))) unsigned int* las_t;

// 4 waves per block, one batch element per wave. No inter-wave communication.
__global__ __launch_bounds__(256) void ctc_alpha_kernel(
        const float* __restrict__ pred,   // (B, T, C) log-probs
        const float* __restrict__ lab,    // (B, S, C)
        float* __restrict__ out_b) {      // (B,) nll/S
    const int wid  = threadIdx.x >> 6;
    const int lane = threadIdx.x & 63;
    const int b = blockIdx.x * 4 + wid;

    __shared__ int   cls_tab[4][NSLOT];
    __shared__ float lps[4][NELEM + 64];   // +64 pad: prefetch ring overrun

    // ---- Phase A: targets[s] = argmax_c lab[b,s,c], first-index tie-break ----
    // Two rows per pass: lanes 0-31 handle row 2sp, lanes 32-63 row 2sp+1.
    // Packed u64 key = fkey(value)<<32 | ~idx  -> max key == (max val, min idx).
    const int half = lane >> 5;          // which row of the pair
    const int li   = lane & 31;
    const float* lrow = lab + (size_t)b * S_ * C_ + (size_t)half * C_ + li;
    float vv[8][4];
    #pragma unroll
    for (int sp = 0; sp < 8; ++sp)
        #pragma unroll
        for (int k = 0; k < 4; ++k)
            vv[sp][k] = lrow[(size_t)sp * 2 * C_ + k * 32];   // 32 indep loads

    if (lane == 0) cls_tab[wid][0] = 0;   // blank class
    #pragma unroll
    for (int sp = 0; sp < 8; ++sp) {
        unsigned long long key = 0;
        #pragma unroll
        for (int k = 0; k < 4; ++k) {
            unsigned long long kk =
                ((unsigned long long)fkey(vv[sp][k]) << 32) | (unsigned)(~(li + 32 * k));
            if (kk > key) key = kk;
        }
        #pragma unroll
        for (int off = 16; off >= 1; off >>= 1) {
            unsigned long long ok = __shfl_xor(key, off, 64);  // stays in half
            if (ok > key) key = ok;
        }
        if (li == 0) cls_tab[wid][1 + sp * 2 + half] = (int)(~(unsigned)key) & 127;
    }
    asm volatile("s_waitcnt lgkmcnt(0)" ::: "memory");   // cls_tab visible in-wave

    // ---- Phase B: stage lp[t][slot] into LDS, two 64-timestep chunks ----
    // e = i*64+lane -> t = e/17, slot = e%17; LDS dest linear in lane.
    const float* pb = pred + (size_t)b * T_ * C_;
    float* mylds = lps[wid];
    #pragma unroll
    for (int i = 0; i < 34; ++i) {       // i<17: t in [0,64) ; i>=17: t in [64,128)
        unsigned e = i * 64 + lane;
        unsigned t = e / NSLOT;
        unsigned s = e - t * NSLOT;
        int c = cls_tab[wid][s];
        const float* src = pb + (size_t)t * C_ + c;
        __builtin_amdgcn_global_load_lds((gas_t)src, (las_t)(mylds + i * 64), 4, 0, 0);
    }

    // ---- Phase C: alpha recursion in log2 domain ----
    const int l = lane;
    int cidx = 0;
    bool skipv = false;
    if (l < L_ && (l & 1)) {
        cidx = 1 + ((l - 1) >> 1);
        if (l >= 3) skipv = (cls_tab[wid][cidx] != cls_tab[wid][cidx - 1]);
    }
    const bool has2 = (l >= 1);

    asm volatile("s_waitcnt vmcnt(17)" ::: "memory");    // chunk A (t<64) ready

    float beta = (l <= 1) ? mylds[cidx] * LOG2E : NEGB;  // t = 0
    float lpA = mylds[1 * NSLOT + cidx];
    float lpB = mylds[2 * NSLOT + cidx];
    float lpC = mylds[3 * NSLOT + cidx];

    #pragma unroll 4
    for (int t = 1; t <= 60; ++t) {      // reads up to t+3=63: chunk A only
        float lp = lpA; lpA = lpB; lpB = lpC;
        lpC = mylds[(t + 3) * NSLOT + cidx];
        float a2 = __shfl_up(beta, 1, 64);
        float a3 = __shfl_up(beta, 2, 64);
        a2 = has2  ? a2 : NEGB;
        a3 = skipv ? a3 : NEGB;
        float m = fmaxf(fmaxf(beta, a2), a3);            // v_max3_f32
        float s = hexp2(beta - m) + hexp2(a2 - m) + hexp2(a3 - m);
        beta = fmaf(lp, LOG2E, m + hlog2(s));
    }

    asm volatile("s_waitcnt vmcnt(0)" ::: "memory");     // chunk B ready

    #pragma unroll 4
    for (int t = 61; t < T_; ++t) {      // pad region covers t+3 up to 130
        float lp = lpA; lpA = lpB; lpB = lpC;
        lpC = mylds[(t + 3) * NSLOT + cidx];
        float a2 = __shfl_up(beta, 1, 64);
        float a3 = __shfl_up(beta, 2, 64);
        a2 = has2  ? a2 : NEGB;
        a3 = skipv ? a3 : NEGB;
        float m = fmaxf(fmaxf(beta, a2), a3);
        float s = hexp2(beta - m) + hexp2(a2 - m) + hexp2(a3 - m);
        beta = fmaf(lp, LOG2E, m + hlog2(s));
    }

    float b31 = __shfl(beta, L_ - 2, 64);
    float b32 = __shfl(beta, L_ - 1, 64);
    if (lane == 0) {
        float m = fmaxf(b31, b32);
        float lse2 = m + hlog2(hexp2(b31 - m) + hexp2(b32 - m));
        float nll = -lse2 * LN2;
        if (!isfinite(nll)) nll = 0.0f;  // zero_infinity
        out_b[b] = nll * (1.0f / (float)S_);
    }
}

__global__ __launch_bounds__(256) void reduce_mean_kernel(
        const float* __restrict__ in, float* __restrict__ out) {
    __shared__ float sm[256];
    const int tid = threadIdx.x;
    float v[16];
    #pragma unroll
    for (int i = 0; i < 16; ++i) v[i] = in[tid + i * 256];
    float s = 0.f;
    #pragma unroll
    for (int i = 0; i < 16; ++i) s += v[i];
    sm[tid] = s;
    __syncthreads();
    for (int w = 128; w >= 1; w >>= 1) {
        if (tid < w) sm[tid] += sm[tid + w];
        __syncthreads();
    }
    if (tid == 0) out[0] = sm[0] / (float)B_;
}

extern "C" void kernel_launch(void* const* d_in, const int* in_sizes, int n_in,
                              void* d_out, int out_size, void* d_ws, size_t ws_size,
                              hipStream_t stream) {
    const float* pred = (const float*)d_in[0];  // (B,T,C) fp32
    const float* lab  = (const float*)d_in[1];  // (B,S,C) fp32
    float* ws = (float*)d_ws;                   // B floats of scratch
    ctc_alpha_kernel<<<B_ / 4, 256, 0, stream>>>(pred, lab, ws);
    reduce_mean_kernel<<<1, 256, 0, stream>>>(ws, (float*)d_out);
}